// Round 1
// baseline (178.157 us; speedup 1.0000x reference)
//
#include <hip/hip_runtime.h>

// LSTM(units=64) over T=5, D_IN=1, then Dense(1, relu).
// Strategy: fp16 MFMA for h@U (fp32 accumulate), gates in fp32 VALU.
// Block = 256 threads (4 waves) handles 64 batch rows.
// Wave w owns gate-columns j in [w*16, w*16+16) of all 4 gates ->
//   U B-fragments are resident in 32 VGPRs for the whole kernel.
// h goes through double-buffered LDS (f16, row stride 72 to dodge bank
// conflicts) so each timestep's A-fragments are one ds_read_b128 each.
// c stays in registers in MFMA C/D layout (col=lane&15, row=quad*4+reg).

typedef _Float16 f16x8 __attribute__((ext_vector_type(8)));
typedef float f32x4 __attribute__((ext_vector_type(4)));

#define MB 64        // batch rows per block
#define NTHREADS 256
#define HSTR 72      // padded f16 row stride for h buffer

__device__ __forceinline__ float fast_exp(float x) {
    // e^x = 2^(x*log2e), v_exp_f32
    return __expf(x);
}
__device__ __forceinline__ float fast_sigmoid(float x) {
    return __builtin_amdgcn_rcpf(1.0f + fast_exp(-x));
}
__device__ __forceinline__ float fast_tanh(float x) {
    // 1 - 2/(1+exp(2x)): exact at 0, robust at +/-inf (no NaN path)
    return __builtin_fmaf(-2.0f, __builtin_amdgcn_rcpf(1.0f + fast_exp(2.0f * x)), 1.0f);
}

__global__ __launch_bounds__(NTHREADS) void lstm_fused(
    const float* __restrict__ x,   // [B,5,1]
    const float* __restrict__ W,   // [1,256]  gate order i,f,g,o
    const float* __restrict__ U,   // [64,256]
    const float* __restrict__ b,   // [256]
    const float* __restrict__ Wd,  // [64,1]
    const float* __restrict__ bd,  // [1]
    float* __restrict__ out,       // [B,1]
    int B)
{
    __shared__ _Float16 hbuf[2][64 * HSTR];   // 18.4 KB
    __shared__ float xs[MB * 5];              // 1.25 KB
    __shared__ float red[4][64];              // 1 KB

    const int tid  = threadIdx.x;
    const int wv   = tid >> 6;     // wave 0..3
    const int lane = tid & 63;
    const int l15  = lane & 15;
    const int quad = lane >> 4;
    const int row0 = blockIdx.x * MB;

    // stage x tile (coalesced)
    for (int i = tid; i < MB * 5; i += NTHREADS) xs[i] = x[row0 * 5 + i];

    // preload U fragments (B operand: n = lane&15, k = quad*8 + j (+32*kh)),
    // plus this wave's W/b slice. ncol = j-column within each gate block.
    const int ncol = wv * 16 + l15;
    f16x8 Bf[4][2];
    float Wf[4], bf[4];
#pragma unroll
    for (int g = 0; g < 4; ++g) {
        const int n = g * 64 + ncol;
        Wf[g] = W[n];
        bf[g] = b[n];
#pragma unroll
        for (int kh = 0; kh < 2; ++kh) {
            f16x8 v;
#pragma unroll
            for (int j = 0; j < 8; ++j) {
                const int k = kh * 32 + quad * 8 + j;
                v[j] = (_Float16)U[k * 256 + n];
            }
            Bf[g][kh] = v;
        }
    }

    // cell state in registers, C/D layout: cell (rt,r) is row rt*16+quad*4+r
    float c[4][4];
#pragma unroll
    for (int a = 0; a < 4; ++a)
#pragma unroll
        for (int r = 0; r < 4; ++r) c[a][r] = 0.0f;

    __syncthreads();  // xs visible

    for (int t = 0; t < 5; ++t) {
        const int src = (t + 1) & 1;   // h produced at t-1
        const int dst = t & 1;
        if (t > 0) __syncthreads();    // all waves' h(t-1) slices visible
#pragma unroll
        for (int rt = 0; rt < 4; ++rt) {
            f32x4 acc[4];
            if (t > 0) {
                const int arow = rt * 16 + l15;  // A layout: m = lane&15
                const f16x8 a0 = *(const f16x8*)&hbuf[src][arow * HSTR + quad * 8];
                const f16x8 a1 = *(const f16x8*)&hbuf[src][arow * HSTR + 32 + quad * 8];
#pragma unroll
                for (int g = 0; g < 4; ++g) {
                    f32x4 z = {0.f, 0.f, 0.f, 0.f};
                    z = __builtin_amdgcn_mfma_f32_16x16x32_f16(a0, Bf[g][0], z, 0, 0, 0);
                    z = __builtin_amdgcn_mfma_f32_16x16x32_f16(a1, Bf[g][1], z, 0, 0, 0);
                    acc[g] = z;
                }
            } else {
#pragma unroll
                for (int g = 0; g < 4; ++g) acc[g] = (f32x4){0.f, 0.f, 0.f, 0.f};
            }
#pragma unroll
            for (int r = 0; r < 4; ++r) {
                const int rloc = rt * 16 + quad * 4 + r;   // C/D row
                const float xv = xs[rloc * 5 + t];
                const float zi = acc[0][r] + xv * Wf[0] + bf[0];
                const float zf = acc[1][r] + xv * Wf[1] + bf[1];
                const float zg = acc[2][r] + xv * Wf[2] + bf[2];
                const float zo = acc[3][r] + xv * Wf[3] + bf[3];
                const float ig = fast_sigmoid(zi);
                const float fg = fast_sigmoid(zf);
                const float gg = fast_tanh(zg);
                const float og = fast_sigmoid(zo);
                const float cn = fg * c[rt][r] + ig * gg;   // t=0: c=0 -> i*g
                c[rt][r] = cn;
                const float hv = og * fast_tanh(cn);
                hbuf[dst][rloc * HSTR + ncol] = (_Float16)hv;
            }
        }
    }

    __syncthreads();  // h(t=4) complete in hbuf[0]

    // Dense(1, relu): out[row] = relu(sum_j h[row][j]*Wd[j] + bd)
    {
        const int row = tid & 63;
        const int q   = tid >> 6;
        float s = 0.0f;
#pragma unroll
        for (int j = 0; j < 16; ++j)
            s += (float)hbuf[0][row * HSTR + q * 16 + j] * Wd[q * 16 + j];
        red[q][row] = s;
    }
    __syncthreads();
    if (tid < 64) {
        const float r = red[0][tid] + red[1][tid] + red[2][tid] + red[3][tid] + bd[0];
        out[row0 + tid] = fmaxf(r, 0.0f);
    }
}

extern "C" void kernel_launch(void* const* d_in, const int* in_sizes, int n_in,
                              void* d_out, int out_size, void* d_ws, size_t ws_size,
                              hipStream_t stream) {
    const float* x  = (const float*)d_in[0];
    const float* W  = (const float*)d_in[1];
    const float* U  = (const float*)d_in[2];
    const float* b  = (const float*)d_in[3];
    const float* Wd = (const float*)d_in[4];
    const float* bd = (const float*)d_in[5];
    float* out = (float*)d_out;
    const int B = in_sizes[0] / 5;
    const int grid = B / MB;   // B = 262144 -> 4096 blocks
    lstm_fused<<<grid, NTHREADS, 0, stream>>>(x, W, U, b, Wd, bd, out, B);
}

// Round 2
// 151.721 us; speedup vs baseline: 1.1742x; 1.1742x over previous
//
#include <hip/hip_runtime.h>

// LSTM(units=64) over T=5, D_IN=1, then Dense(1, relu).  R2.
// fp16 MFMA for h@U (fp32 acc), gates in fp32 VALU via exp2 forms.
// Block = 256 threads (4 waves) = 64 batch rows.
// Wave w owns gate-columns [w*16, w*16+16) of all 4 gates; U B-fragments
// pre-scaled by -log2e (i,f,o) / +2log2e (g) live in 32 VGPRs for the
// whole kernel -- __launch_bounds__(256,2) lifts the VGPR cap so the
// compiler doesn't rematerialize them per timestep (R1: VGPR=60 + ~90
// extra cyc/cell-set of VALU issue = remat signature).
// Bias + x*W folded into the MFMA C operand (no post-MFMA add).
// h round-trips LDS f16 (stride 72); c stays in regs in C/D layout.

typedef _Float16 f16x8 __attribute__((ext_vector_type(8)));
typedef float f32x4 __attribute__((ext_vector_type(4)));

#define MB 64
#define NTHREADS 256
#define HSTR 72

__device__ __forceinline__ float ex2(float x) { return __builtin_amdgcn_exp2f(x); }
__device__ __forceinline__ float rcp(float x) { return __builtin_amdgcn_rcpf(x); }

__global__ __launch_bounds__(NTHREADS, 2) void lstm_fused(
    const float* __restrict__ x,   // [B,5,1]
    const float* __restrict__ W,   // [1,256]  gate order i,f,g,o
    const float* __restrict__ U,   // [64,256]
    const float* __restrict__ b,   // [256]
    const float* __restrict__ Wd,  // [64,1]
    const float* __restrict__ bd,  // [1]
    float* __restrict__ out,       // [B,1]
    int B)
{
    __shared__ _Float16 hbuf[2][64 * HSTR];   // 18.4 KB
    __shared__ float xs[MB * 5];              // 1.25 KB
    __shared__ float red[4][64];              // 1 KB

    const int tid  = threadIdx.x;
    const int wv   = tid >> 6;
    const int lane = tid & 63;
    const int l15  = lane & 15;
    const int quad = lane >> 4;
    const int row0 = blockIdx.x * MB;

    for (int i = tid; i < MB * 5; i += NTHREADS) xs[i] = x[row0 * 5 + i];

    const float LOG2E = 1.44269504f;
    // gate scales: sigmoid gates get -log2e (so z feeds exp2 directly for
    // sigmoid = rcp(1+exp2(-z*log2e))); tanh gate gets +2log2e
    // (tanh(z) = 1 - 2*rcp(1+exp2(2z*log2e))).
    const float gscale[4] = {-LOG2E, -LOG2E, 2.0f * LOG2E, -LOG2E};

    // U B-fragments: n = lane&15 (+gate*64), k = kh*32 + quad*8 + j
    const int ncol = wv * 16 + l15;
    f16x8 Bf[4][2];
    float Wf[4], bf[4];
#pragma unroll
    for (int g = 0; g < 4; ++g) {
        const int n = g * 64 + ncol;
        const float s = gscale[g];
        Wf[g] = W[n] * s;
        bf[g] = b[n] * s;
#pragma unroll
        for (int kh = 0; kh < 2; ++kh) {
            f16x8 v;
#pragma unroll
            for (int j = 0; j < 8; ++j) {
                const int k = kh * 32 + quad * 8 + j;
                v[j] = (_Float16)(U[k * 256 + n] * s);
            }
            Bf[g][kh] = v;
        }
    }

    float c[4][4];
#pragma unroll
    for (int a = 0; a < 4; ++a)
#pragma unroll
        for (int r = 0; r < 4; ++r) c[a][r] = 0.0f;

    __syncthreads();  // xs visible

    // ---- t = 0 (h=0, c=0: no MFMA; c = i*g, h = o*tanh(c)) ----
#pragma unroll
    for (int rt = 0; rt < 4; ++rt) {
#pragma unroll
        for (int r = 0; r < 4; ++r) {
            const int rloc = rt * 16 + quad * 4 + r;
            const float xv = xs[rloc * 5 + 0];
            const float zi = __builtin_fmaf(xv, Wf[0], bf[0]);
            const float zf = __builtin_fmaf(xv, Wf[1], bf[1]);  (void)zf;
            const float zg = __builtin_fmaf(xv, Wf[2], bf[2]);
            const float zo = __builtin_fmaf(xv, Wf[3], bf[3]);
            const float ig = rcp(1.0f + ex2(zi));
            const float gg = __builtin_fmaf(-2.0f, rcp(1.0f + ex2(zg)), 1.0f);
            const float og = rcp(1.0f + ex2(zo));
            const float cn = ig * gg;
            c[rt][r] = cn;
            const float sc = cn * (2.0f * LOG2E);
            const float th = __builtin_fmaf(-2.0f, rcp(1.0f + ex2(sc)), 1.0f);
            hbuf[0][rloc * HSTR + ncol] = (_Float16)(og * th);
        }
    }

    // ---- t = 1..4 ----
#pragma unroll
    for (int t = 1; t < 5; ++t) {
        const int src = (t + 1) & 1;
        const int dst = t & 1;
        __syncthreads();
#pragma unroll
        for (int rt = 0; rt < 4; ++rt) {
            const int arow = rt * 16 + l15;   // A layout: m = lane&15
            const f16x8 a0 = *(const f16x8*)&hbuf[src][arow * HSTR + quad * 8];
            const f16x8 a1 = *(const f16x8*)&hbuf[src][arow * HSTR + 32 + quad * 8];
            // C init = x*W + b (pre-scaled), in C/D layout rows
            float xv[4];
#pragma unroll
            for (int r = 0; r < 4; ++r)
                xv[r] = xs[(rt * 16 + quad * 4 + r) * 5 + t];
            f32x4 acc[4];
#pragma unroll
            for (int g = 0; g < 4; ++g) {
                f32x4 z;
#pragma unroll
                for (int r = 0; r < 4; ++r)
                    z[r] = __builtin_fmaf(xv[r], Wf[g], bf[g]);
                z = __builtin_amdgcn_mfma_f32_16x16x32_f16(a0, Bf[g][0], z, 0, 0, 0);
                z = __builtin_amdgcn_mfma_f32_16x16x32_f16(a1, Bf[g][1], z, 0, 0, 0);
                acc[g] = z;
            }
#pragma unroll
            for (int r = 0; r < 4; ++r) {
                const int rloc = rt * 16 + quad * 4 + r;
                const float ig = rcp(1.0f + ex2(acc[0][r]));
                const float fg = rcp(1.0f + ex2(acc[1][r]));
                const float gg = __builtin_fmaf(-2.0f, rcp(1.0f + ex2(acc[2][r])), 1.0f);
                const float og = rcp(1.0f + ex2(acc[3][r]));
                const float cn = __builtin_fmaf(fg, c[rt][r], ig * gg);
                c[rt][r] = cn;
                const float sc = cn * (2.0f * LOG2E);
                const float th = __builtin_fmaf(-2.0f, rcp(1.0f + ex2(sc)), 1.0f);
                hbuf[dst][rloc * HSTR + ncol] = (_Float16)(og * th);
            }
        }
    }

    __syncthreads();  // h(t=4) complete in hbuf[0]

    // Dense(1, relu)
    {
        const int row = tid & 63;
        const int q   = tid >> 6;
        float s = 0.0f;
#pragma unroll
        for (int j = 0; j < 16; ++j)
            s += (float)hbuf[0][row * HSTR + q * 16 + j] * Wd[q * 16 + j];
        red[q][row] = s;
    }
    __syncthreads();
    if (tid < 64) {
        const float r = red[0][tid] + red[1][tid] + red[2][tid] + red[3][tid] + bd[0];
        out[row0 + tid] = fmaxf(r, 0.0f);
    }
}

extern "C" void kernel_launch(void* const* d_in, const int* in_sizes, int n_in,
                              void* d_out, int out_size, void* d_ws, size_t ws_size,
                              hipStream_t stream) {
    const float* x  = (const float*)d_in[0];
    const float* W  = (const float*)d_in[1];
    const float* U  = (const float*)d_in[2];
    const float* b  = (const float*)d_in[3];
    const float* Wd = (const float*)d_in[4];
    const float* bd = (const float*)d_in[5];
    float* out = (float*)d_out;
    const int B = in_sizes[0] / 5;
    const int grid = B / MB;   // 4096 blocks
    lstm_fused<<<grid, NTHREADS, 0, stream>>>(x, W, U, b, Wd, bd, out, B);
}